// Round 1
// baseline (28956.863 us; speedup 1.0000x reference)
//
#include <hip/hip_runtime.h>
#include <hip/hip_bf16.h>
#include <hip/hip_cooperative_groups.h>

namespace cg = cooperative_groups;

#define T_SZ   128
#define DPV    10

// Inputs fp32, OUTPUT fp32. Internals: weights fp32->bf16 once, GEMMs on
// bf16 MFMA with fp32 accumulation, fp32 c-master, fp32 gates_h carry.
// Single persistent cooperative kernel: 256 blocks x 512 threads (1/CU),
// 3 grid.sync() per timestep replacing 3 kernel launches per timestep.

typedef __attribute__((ext_vector_type(8))) short bfrag8;
typedef __attribute__((ext_vector_type(4))) float floatx4;

#define MFMA __builtin_amdgcn_mfma_f32_16x16x32_bf16

static __device__ __forceinline__ bfrag8 load8(const __hip_bfloat16* p) {
    return *(const bfrag8*)(const void*)p;  // 16B-aligned by construction
}
static __device__ __forceinline__ float sigm(float x) {
    return 1.0f / (1.0f + __expf(-x));
}

// ---------------------------------------------------------------------------
// One-time weight conversion: fp32 -> bf16 for W1, W3, Wih, Whh.
// ---------------------------------------------------------------------------
__global__ __launch_bounds__(256) void pack_kernel(
    const float* __restrict__ W1, const float* __restrict__ W3,
    const float* __restrict__ Wih, const float* __restrict__ Whh,
    __hip_bfloat16* __restrict__ W1b, __hip_bfloat16* __restrict__ W3b,
    __hip_bfloat16* __restrict__ Wihb, __hip_bfloat16* __restrict__ Whhb)
{
    const size_t e = ((size_t)blockIdx.x * 256 + threadIdx.x) * 8;
    const float* src; __hip_bfloat16* dst; size_t off;
    if (e < 524288)        { src = W1;  dst = W1b;  off = e; }
    else if (e < 1048576)  { src = W3;  dst = W3b;  off = e - 524288; }
    else if (e < 2097152)  { src = Wih; dst = Wihb; off = e - 1048576; }
    else                   { src = Whh; dst = Whhb; off = e - 2097152; }
#pragma unroll
    for (int j = 0; j < 8; ++j) dst[off + j] = __float2bfloat16(src[off + j]);
}

// ---------------------------------------------------------------------------
// Persistent recurrence kernel.
// MFMA 16x16x32_bf16 layouts (HW-verified in prior session):
//   A-frag: lane l holds A[m=l&15][k=(l>>4)*8+j]
//   B-frag: lane l holds W[n=l&15][k]  (K-contig row-major weights)
//   C/D:    lane l reg r -> row=(l>>4)*4+r, col=l&15
//
// Phase 1:
//   blk <  64 : z1 = relu([h|c] @ W1^T + b1), 128x64 tiles  (K=1024 dual)
//   blk < 192 : gh = h @ Whh^T (fp32, no act), 128x128 tiles (K=512)
//   else      : z2 = relu(sv[:,t,:] @ W2^T + b2), 16 rows/block (K=10 GEMV)
// Phase 2: x = relu(z1@W3[:,:512]^T + z2@W3[:,512:]^T + b3), 64x32 tiles
// Phase 3: gates = x@Wih^T + gh + bih + bhh; LSTM cell; c32/cbf/h/out.
// ---------------------------------------------------------------------------
__global__ __launch_bounds__(512) void rnn_kernel(
    const float* __restrict__ sv,
    const float* __restrict__ W2, const float* __restrict__ b2,
    const __hip_bfloat16* __restrict__ W1b, const float* __restrict__ b1,
    const __hip_bfloat16* __restrict__ W3b, const float* __restrict__ b3,
    const __hip_bfloat16* __restrict__ Wihb, const __hip_bfloat16* __restrict__ Whhb,
    const float* __restrict__ bih, const float* __restrict__ bhh,
    float* __restrict__ c32, __hip_bfloat16* __restrict__ cbf,
    __hip_bfloat16* __restrict__ hbuf,
    __hip_bfloat16* __restrict__ z1, __hip_bfloat16* __restrict__ z2,
    __hip_bfloat16* __restrict__ xbuf, float* __restrict__ gh,
    float* __restrict__ out)
{
    cg::grid_group grid = cg::this_grid();
    const int blk  = blockIdx.x;
    const int tid  = threadIdx.x;
    const int wave = tid >> 6;
    const int lane = tid & 63;
    const int l15  = lane & 15;
    const int quad = lane >> 4;

    for (int t = 0; t < T_SZ; ++t) {
        // ------------------------------ phase 1 ------------------------------
        if (blk < 64) {
            // z1: 128x64 tile, 8 waves x 16 rows, dual-K [h | c]
            const int tile_m = (blk >> 3) * 128;
            const int tile_n = (blk & 7) * 64;
            const int arow = tile_m + wave * 16 + l15;
            const __hip_bfloat16* a1 = hbuf + (size_t)arow * 512 + quad * 8;
            const __hip_bfloat16* a2 = cbf  + (size_t)arow * 512 + quad * 8;
            const __hip_bfloat16* wr = W1b + (size_t)(tile_n + l15) * 1024 + quad * 8;
            floatx4 acc0 = {0.f,0.f,0.f,0.f};
            floatx4 acc1 = acc0, acc2 = acc0, acc3 = acc0;
            for (int k0 = 0; k0 < 512; k0 += 32) {
                bfrag8 a = load8(a1 + k0);
                acc0 = MFMA(a, load8(wr + k0),                       acc0, 0,0,0);
                acc1 = MFMA(a, load8(wr + (size_t)16*1024 + k0),     acc1, 0,0,0);
                acc2 = MFMA(a, load8(wr + (size_t)32*1024 + k0),     acc2, 0,0,0);
                acc3 = MFMA(a, load8(wr + (size_t)48*1024 + k0),     acc3, 0,0,0);
            }
            for (int k0 = 0; k0 < 512; k0 += 32) {
                bfrag8 a = load8(a2 + k0);
                acc0 = MFMA(a, load8(wr + 512 + k0),                   acc0, 0,0,0);
                acc1 = MFMA(a, load8(wr + (size_t)16*1024 + 512 + k0), acc1, 0,0,0);
                acc2 = MFMA(a, load8(wr + (size_t)32*1024 + 512 + k0), acc2, 0,0,0);
                acc3 = MFMA(a, load8(wr + (size_t)48*1024 + 512 + k0), acc3, 0,0,0);
            }
            const int row = tile_m + wave * 16 + quad * 4;
            floatx4 accs[4] = {acc0, acc1, acc2, acc3};
#pragma unroll
            for (int c = 0; c < 4; ++c) {
                const int col = tile_n + c * 16 + l15;
                const float bv = b1[col];
#pragma unroll
                for (int r = 0; r < 4; ++r)
                    z1[(size_t)(row + r) * 512 + col] =
                        __float2bfloat16(fmaxf(accs[c][r] + bv, 0.0f));
            }
        } else if (blk < 192) {
            // gates_h = h @ Whh^T : 128x128 tile, fp32 out (no bias/act)
            const int bb = blk - 64;
            const int tile_m = (bb >> 4) * 128;
            const int tile_n = (bb & 15) * 128;
            const int arow = tile_m + wave * 16 + l15;
            const __hip_bfloat16* a1 = hbuf + (size_t)arow * 512 + quad * 8;
            const __hip_bfloat16* wr = Whhb + (size_t)(tile_n + l15) * 512 + quad * 8;
            floatx4 acc[8];
#pragma unroll
            for (int c = 0; c < 8; ++c) acc[c] = (floatx4){0.f,0.f,0.f,0.f};
            for (int k0 = 0; k0 < 512; k0 += 32) {
                bfrag8 a = load8(a1 + k0);
#pragma unroll
                for (int c = 0; c < 8; ++c)
                    acc[c] = MFMA(a, load8(wr + (size_t)(c * 16) * 512 + k0), acc[c], 0,0,0);
            }
            const int row = tile_m + wave * 16 + quad * 4;
#pragma unroll
            for (int c = 0; c < 8; ++c) {
                const int col = tile_n + c * 16 + l15;
#pragma unroll
                for (int r = 0; r < 4; ++r)
                    gh[(size_t)(row + r) * 2048 + col] = acc[c][r];
            }
        } else {
            // z2 = relu(sv_t @ W2^T + b2): 16 rows x 512 cols per block
            const int r  = (blk - 192) * 16 + (tid >> 5);
            const int cl = tid & 31;
            const float* svp = sv + ((size_t)r * T_SZ + t) * DPV;
            float sva[DPV];
#pragma unroll
            for (int k = 0; k < DPV; ++k) sva[k] = svp[k];
#pragma unroll
            for (int j = 0; j < 16; ++j) {
                const int col = cl + j * 32;
                const float* wrow = W2 + (size_t)col * DPV;
                float acc = b2[col];
#pragma unroll
                for (int k = 0; k < DPV; ++k) acc += sva[k] * wrow[k];
                z2[(size_t)r * 512 + col] = __float2bfloat16(fmaxf(acc, 0.0f));
            }
        }
        grid.sync();
        // ------------------------------ phase 2 ------------------------------
        {
            // x = relu(z1@W3a^T + z2@W3b^T + b3): 64x32 tiles, all 256 blocks
            const int tile_m = (blk >> 4) * 64;
            const int ncol   = (blk & 15) * 32 + (wave & 1) * 16;
            const int arow   = tile_m + (wave >> 1) * 16 + l15;
            const __hip_bfloat16* a1 = z1 + (size_t)arow * 512 + quad * 8;
            const __hip_bfloat16* a2 = z2 + (size_t)arow * 512 + quad * 8;
            const __hip_bfloat16* wr = W3b + (size_t)(ncol + l15) * 1024 + quad * 8;
            floatx4 accA = {0.f,0.f,0.f,0.f}, accB = accA;
            for (int k0 = 0; k0 < 512; k0 += 32) {
                accA = MFMA(load8(a1 + k0), load8(wr + k0),       accA, 0,0,0);
                accB = MFMA(load8(a2 + k0), load8(wr + 512 + k0), accB, 0,0,0);
            }
            const int row = tile_m + (wave >> 1) * 16 + quad * 4;
            const int col = ncol + l15;
            const float bv = b3[col];
#pragma unroll
            for (int r = 0; r < 4; ++r)
                xbuf[(size_t)(row + r) * 512 + col] =
                    __float2bfloat16(fmaxf(accA[r] + accB[r] + bv, 0.0f));
        }
        grid.sync();
        // ------------------------------ phase 3 ------------------------------
        {
            // gates = x@Wih^T + gh + (bih+bhh); LSTM cell update
            const int tile_m = (blk >> 4) * 64;
            const int j0 = (blk & 15) * 32 + (wave & 1) * 16;
            const int arow = tile_m + (wave >> 1) * 16 + l15;
            const __hip_bfloat16* xr = xbuf + (size_t)arow * 512 + quad * 8;
            const __hip_bfloat16* wi = Wihb + (size_t)(j0 + l15) * 512 + quad * 8;
            floatx4 acc[4];
#pragma unroll
            for (int g = 0; g < 4; ++g) acc[g] = (floatx4){0.f,0.f,0.f,0.f};
            for (int k0 = 0; k0 < 512; k0 += 32) {
                bfrag8 a = load8(xr + k0);
#pragma unroll
                for (int g = 0; g < 4; ++g)
                    acc[g] = MFMA(a, load8(wi + (size_t)(g * 512) * 512 + k0), acc[g], 0,0,0);
            }
            const int row = tile_m + (wave >> 1) * 16 + quad * 4;
            const int j = j0 + l15;
            const float bi = bih[j]        + bhh[j];
            const float bf = bih[512 + j]  + bhh[512 + j];
            const float bg = bih[1024 + j] + bhh[1024 + j];
            const float bo = bih[1536 + j] + bhh[1536 + j];
#pragma unroll
            for (int r = 0; r < 4; ++r) {
                const int rr = row + r;
                const float* ghr = gh + (size_t)rr * 2048 + j;
                const float iv = sigm(acc[0][r] + ghr[0]    + bi);
                const float fv = sigm(acc[1][r] + ghr[512]  + bf);
                const float gv = tanhf(acc[2][r] + ghr[1024] + bg);
                const float ov = sigm(acc[3][r] + ghr[1536] + bo);
                const float cn = fv * c32[(size_t)rr * 512 + j] + iv * gv;
                const float hv = ov * tanhf(cn);
                c32[(size_t)rr * 512 + j]  = cn;
                cbf[(size_t)rr * 512 + j]  = __float2bfloat16(cn);
                hbuf[(size_t)rr * 512 + j] = __float2bfloat16(hv);
                out[((size_t)rr * T_SZ + t) * 512 + j] = hv;   // fp32 output
            }
        }
        grid.sync();
    }
}

// ---------------------------------------------------------------------------
// Workspace layout (22 MB):
//   0 MB  c32   fp32 [1024x512]   (2 MB)
//   2 MB  cbf   bf16 [1024x512]   (1 MB)
//   3 MB  z1    bf16 [1024x512]   (1 MB)
//   4 MB  z2    bf16 [1024x512]   (1 MB)
//   5 MB  x     bf16 [1024x512]   (1 MB)
//   6 MB  h     bf16 [1024x512]   (1 MB)
//   8 MB  gh    fp32 [1024x2048]  (8 MB)
//  16 MB  W1b   bf16 [512x1024]   (1 MB)
//  17 MB  W3b   bf16 [512x1024]   (1 MB)
//  18 MB  Wihb  bf16 [2048x512]   (2 MB)
//  20 MB  Whhb  bf16 [2048x512]   (2 MB)
// ---------------------------------------------------------------------------
extern "C" void kernel_launch(void* const* d_in, const int* in_sizes, int n_in,
                              void* d_out, int out_size, void* d_ws, size_t ws_size,
                              hipStream_t stream) {
    (void)in_sizes; (void)n_in; (void)out_size; (void)ws_size;

    const float* sv  = (const float*)d_in[0];
    const float* W1  = (const float*)d_in[1];
    const float* b1  = (const float*)d_in[2];
    const float* W2  = (const float*)d_in[3];
    const float* b2  = (const float*)d_in[4];
    const float* W3  = (const float*)d_in[5];
    const float* b3  = (const float*)d_in[6];
    const float* Wih = (const float*)d_in[7];
    const float* Whh = (const float*)d_in[8];
    const float* bih = (const float*)d_in[9];
    const float* bhh = (const float*)d_in[10];
    float* out = (float*)d_out;

    char* w = (char*)d_ws;
    float*          c32  = (float*)         (w);
    __hip_bfloat16* cbf  = (__hip_bfloat16*)(w + (size_t)(2 << 20));
    __hip_bfloat16* z1   = (__hip_bfloat16*)(w + (size_t)(3 << 20));
    __hip_bfloat16* z2   = (__hip_bfloat16*)(w + (size_t)(4 << 20));
    __hip_bfloat16* xb   = (__hip_bfloat16*)(w + (size_t)(5 << 20));
    __hip_bfloat16* hbuf = (__hip_bfloat16*)(w + (size_t)(6 << 20));
    float*          gh   = (float*)         (w + (size_t)(8 << 20));
    __hip_bfloat16* W1b  = (__hip_bfloat16*)(w + (size_t)(16 << 20));
    __hip_bfloat16* W3b  = (__hip_bfloat16*)(w + (size_t)(17 << 20));
    __hip_bfloat16* Wihb = (__hip_bfloat16*)(w + (size_t)(18 << 20));
    __hip_bfloat16* Whhb = (__hip_bfloat16*)(w + (size_t)(20 << 20));

    hipMemsetAsync(c32,  0, (size_t)(2 << 20), stream);  // c0 = 0 (fp32 master)
    hipMemsetAsync(cbf,  0, (size_t)(1 << 20), stream);  // c0 = 0 (bf16 shadow)
    hipMemsetAsync(hbuf, 0, (size_t)(1 << 20), stream);  // h0 = 0

    pack_kernel<<<1536, 256, 0, stream>>>(W1, W3, Wih, Whh, W1b, W3b, Wihb, Whhb);

    void* args[] = {
        (void*)&sv, (void*)&W2, (void*)&b2, (void*)&W1b, (void*)&b1,
        (void*)&W3b, (void*)&b3, (void*)&Wihb, (void*)&Whhb,
        (void*)&bih, (void*)&bhh, (void*)&c32, (void*)&cbf, (void*)&hbuf,
        (void*)&z1, (void*)&z2, (void*)&xb, (void*)&gh, (void*)&out };
    hipLaunchCooperativeKernel(rnn_kernel, dim3(256), dim3(512), args, 0, stream);
}

// Round 2
// 15903.226 us; speedup vs baseline: 1.8208x; 1.8208x over previous
//
#include <hip/hip_runtime.h>
#include <hip/hip_bf16.h>
#include <hip/hip_cooperative_groups.h>

namespace cg = cooperative_groups;

#define T_SZ 128
#define DPV  10

// Cooperative persistent LSTM. 256 blocks x 512 threads (1/CU, 8 waves).
// Block (g8 = blk&7, nu = blk>>3): owns batch rows [g8*128, +128) and
// output cols [nu*16, +16) of every GEMM. Wih/Whh slices live in LDS
// (128 KB, staged once, XOR-swizzled); gate partials and c-state live in
// registers across phases (grid.sync wipes L2 on every XCD, so nothing
// reused across phases may rely on L2).

typedef __attribute__((ext_vector_type(8))) short bfrag8;
typedef __attribute__((ext_vector_type(4))) float floatx4;

#define MFMA __builtin_amdgcn_mfma_f32_16x16x32_bf16

static __device__ __forceinline__ bfrag8 load8(const __hip_bfloat16* p) {
    return *(const bfrag8*)(const void*)p;  // 16B-aligned by construction
}
static __device__ __forceinline__ float sigm(float x) {
    return 1.0f / (1.0f + __expf(-x));
}
// LDS byte address for (row, kbyte) of a [64 rows x 1024B] weight slice,
// XOR-swizzled so 16 lanes reading 16 rows at the same k hit <=2-way banks.
static __device__ __forceinline__ int swz(int row, int kb) {
    return row * 1024 + (kb ^ ((row & 7) << 4));
}

// ---------------------------------------------------------------------------
// One-time weight conversion: fp32 -> bf16 for W1, W3, Wih, Whh.
// ---------------------------------------------------------------------------
__global__ __launch_bounds__(256) void pack_kernel(
    const float* __restrict__ W1, const float* __restrict__ W3,
    const float* __restrict__ Wih, const float* __restrict__ Whh,
    __hip_bfloat16* __restrict__ W1b, __hip_bfloat16* __restrict__ W3b,
    __hip_bfloat16* __restrict__ Wihb, __hip_bfloat16* __restrict__ Whhb)
{
    const size_t e = ((size_t)blockIdx.x * 256 + threadIdx.x) * 8;
    const float* src; __hip_bfloat16* dst; size_t off;
    if (e < 524288)        { src = W1;  dst = W1b;  off = e; }
    else if (e < 1048576)  { src = W3;  dst = W3b;  off = e - 524288; }
    else if (e < 2097152)  { src = Wih; dst = Wihb; off = e - 1048576; }
    else                   { src = Whh; dst = Whhb; off = e - 2097152; }
#pragma unroll
    for (int j = 0; j < 8; ++j) dst[off + j] = __float2bfloat16(src[off + j]);
}

// ---------------------------------------------------------------------------
// MFMA 16x16x32_bf16 layouts (HW-verified in prior session):
//   A-frag: lane l holds A[m=l&15][k=(l>>4)*8+j]
//   B-frag: lane l holds W[n=l&15][k=(l>>4)*8+j]  (K-contig row-major)
//   C/D:    lane l reg r -> row=(l>>4)*4+r, col=l&15
// ---------------------------------------------------------------------------
__global__ __launch_bounds__(512) void rnn_kernel(
    const float* __restrict__ sv,
    const float* __restrict__ W2, const float* __restrict__ b2,
    const __hip_bfloat16* __restrict__ W1b, const float* __restrict__ b1,
    const __hip_bfloat16* __restrict__ W3b, const float* __restrict__ b3,
    const __hip_bfloat16* __restrict__ Wihb, const __hip_bfloat16* __restrict__ Whhb,
    const float* __restrict__ bih, const float* __restrict__ bhh,
    __hip_bfloat16* __restrict__ cbf, __hip_bfloat16* __restrict__ hbuf,
    __hip_bfloat16* __restrict__ z1, __hip_bfloat16* __restrict__ z2,
    __hip_bfloat16* __restrict__ xbuf,
    float* __restrict__ out)
{
    cg::grid_group grid = cg::this_grid();
    __shared__ __align__(16) char lds[131072];   // [0,64K): Wih slice; [64K,128K): Whh slice

    const int blk  = blockIdx.x;
    const int g8   = blk & 7;        // m-group (XCD-affine under round-robin dispatch)
    const int nu   = blk >> 3;       // 0..31 n-slice
    const int m0   = g8 << 7;        // 128 batch rows
    const int j0   = nu << 4;        // 16 output cols
    const int tid  = threadIdx.x;
    const int w    = tid >> 6;
    const int lane = tid & 63;
    const int l15  = lane & 15;
    const int quad = lane >> 4;

    // ---- stage Wih/Whh j-slices into LDS once (64 rows x 512 K, bf16 each) ----
    for (int i = tid; i < 4096; i += 512) {
        const int row  = i >> 6;             // 0..63 = gate*16 + jj
        const int kb   = (i & 63) << 4;      // byte offset, 16B chunks
        const int gate = row >> 4, jj = row & 15;
        const size_t goff = ((size_t)(gate * 512 + j0 + jj)) * 512 + (kb >> 1);
        *(bfrag8*)(lds +         swz(row, kb)) = load8(Wihb + goff);
        *(bfrag8*)(lds + 65536 + swz(row, kb)) = load8(Whhb + goff);
    }
    __syncthreads();

    const int arow = m0 + w * 16 + l15;       // A-fragment row for this lane
    const int orow = m0 + w * 16 + quad * 4;  // output row base (+r)
    const int col  = j0 + l15;                // output col
    const int kq   = quad << 4;               // lane's 16B offset within a K-row

    // per-lane constants, loaded once for all 128 steps
    const float b1v = b1[col];
    const float b3v = b3[col];
    const float b2v = b2[col];
    const float biv = bih[col]        + bhh[col];
    const float bfv = bih[512 + col]  + bhh[512 + col];
    const float bgv = bih[1024 + col] + bhh[1024 + col];
    const float bov = bih[1536 + col] + bhh[1536 + col];
    float w2r[DPV];
#pragma unroll
    for (int k = 0; k < DPV; ++k) w2r[k] = W2[(size_t)col * DPV + k];

    const __hip_bfloat16* hA  = hbuf + (size_t)arow * 512 + quad * 8;
    const __hip_bfloat16* cA  = cbf  + (size_t)arow * 512 + quad * 8;
    const __hip_bfloat16* z1A = z1   + (size_t)arow * 512 + quad * 8;
    const __hip_bfloat16* z2A = z2   + (size_t)arow * 512 + quad * 8;
    const __hip_bfloat16* xA  = xbuf + (size_t)arow * 512 + quad * 8;
    const __hip_bfloat16* w1  = W1b + (size_t)col * 1024 + quad * 8;
    const __hip_bfloat16* w3  = W3b + (size_t)col * 1024 + quad * 8;
    const int xorl = (l15 & 7) << 4;          // lane's LDS swizzle term

    floatx4 creg = {0.f, 0.f, 0.f, 0.f};      // fp32 c-state, register-resident

    for (int t = 0; t < T_SZ; ++t) {
        // ---------------- phase 1: z1, z2, gacc = h@Whh ----------------
        floatx4 az = {0.f, 0.f, 0.f, 0.f};
        floatx4 gacc[4];
#pragma unroll
        for (int G = 0; G < 4; ++G) gacc[G] = (floatx4){0.f, 0.f, 0.f, 0.f};

#pragma unroll
        for (int k0 = 0; k0 < 512; k0 += 32) {
            bfrag8 a = load8(hA + k0);                       // h rows (global, m-local)
            az = MFMA(a, load8(w1 + k0), az, 0, 0, 0);       // z1 h-part
#pragma unroll
            for (int G = 0; G < 4; ++G) {                    // h @ Whh (LDS)
                bfrag8 b = *(const bfrag8*)(lds + 65536 +
                    (G * 16 + l15) * 1024 + ((k0 * 2 + kq) ^ xorl));
                gacc[G] = MFMA(a, b, gacc[G], 0, 0, 0);
            }
        }
#pragma unroll
        for (int k0 = 0; k0 < 512; k0 += 32)                 // z1 c-part
            az = MFMA(load8(cA + k0), load8(w1 + 512 + k0), az, 0, 0, 0);
#pragma unroll
        for (int r = 0; r < 4; ++r)
            z1[(size_t)(orow + r) * 512 + col] =
                __float2bfloat16(fmaxf(az[r] + b1v, 0.f));
        // z2 = relu(sv_t @ W2^T + b2), K=10 scalar
#pragma unroll
        for (int r = 0; r < 4; ++r) {
            const float* svp = sv + ((size_t)(orow + r) * T_SZ + t) * DPV;
            float acc = b2v;
#pragma unroll
            for (int k = 0; k < DPV; ++k) acc += svp[k] * w2r[k];
            z2[(size_t)(orow + r) * 512 + col] = __float2bfloat16(fmaxf(acc, 0.f));
        }
        grid.sync();
        // ---------------- phase 2: x = relu(z1@W3a^T + z2@W3b^T + b3) ----------------
        floatx4 ax = {0.f, 0.f, 0.f, 0.f};
#pragma unroll
        for (int k0 = 0; k0 < 512; k0 += 32) {
            ax = MFMA(load8(z1A + k0), load8(w3 + k0),       ax, 0, 0, 0);
            ax = MFMA(load8(z2A + k0), load8(w3 + 512 + k0), ax, 0, 0, 0);
        }
#pragma unroll
        for (int r = 0; r < 4; ++r)
            xbuf[(size_t)(orow + r) * 512 + col] =
                __float2bfloat16(fmaxf(ax[r] + b3v, 0.f));
        grid.sync();
        // ---------------- phase 3: gacc += x@Wih^T; LSTM cell ----------------
#pragma unroll
        for (int k0 = 0; k0 < 512; k0 += 32) {
            bfrag8 a = load8(xA + k0);
#pragma unroll
            for (int G = 0; G < 4; ++G) {
                bfrag8 b = *(const bfrag8*)(lds +
                    (G * 16 + l15) * 1024 + ((k0 * 2 + kq) ^ xorl));
                gacc[G] = MFMA(a, b, gacc[G], 0, 0, 0);
            }
        }
#pragma unroll
        for (int r = 0; r < 4; ++r) {
            const float iv = sigm(gacc[0][r] + biv);
            const float fv = sigm(gacc[1][r] + bfv);
            const float gv = tanhf(gacc[2][r] + bgv);
            const float ov = sigm(gacc[3][r] + bov);
            const float cn = fv * creg[r] + iv * gv;
            const float hv = ov * tanhf(cn);
            creg[r] = cn;
            cbf [(size_t)(orow + r) * 512 + col] = __float2bfloat16(cn);
            hbuf[(size_t)(orow + r) * 512 + col] = __float2bfloat16(hv);
            out[((size_t)(orow + r) * T_SZ + t) * 512 + col] = hv;  // fp32 output
        }
        grid.sync();
    }
}

// ---------------------------------------------------------------------------
// Workspace layout (11 MB):
//   0 MB  cbf   bf16 [1024x512]   (1 MB)
//   1 MB  z1    bf16 [1024x512]   (1 MB)
//   2 MB  z2    bf16 [1024x512]   (1 MB)
//   3 MB  x     bf16 [1024x512]   (1 MB)
//   4 MB  h     bf16 [1024x512]   (1 MB)
//   5 MB  W1b   bf16 [512x1024]   (1 MB)
//   6 MB  W3b   bf16 [512x1024]   (1 MB)
//   7 MB  Wihb  bf16 [2048x512]   (2 MB)
//   9 MB  Whhb  bf16 [2048x512]   (2 MB)
// ---------------------------------------------------------------------------
extern "C" void kernel_launch(void* const* d_in, const int* in_sizes, int n_in,
                              void* d_out, int out_size, void* d_ws, size_t ws_size,
                              hipStream_t stream) {
    (void)in_sizes; (void)n_in; (void)out_size; (void)ws_size;

    const float* sv  = (const float*)d_in[0];
    const float* W1  = (const float*)d_in[1];
    const float* b1  = (const float*)d_in[2];
    const float* W2  = (const float*)d_in[3];
    const float* b2  = (const float*)d_in[4];
    const float* W3  = (const float*)d_in[5];
    const float* b3  = (const float*)d_in[6];
    const float* Wih = (const float*)d_in[7];
    const float* Whh = (const float*)d_in[8];
    const float* bih = (const float*)d_in[9];
    const float* bhh = (const float*)d_in[10];
    float* out = (float*)d_out;

    char* w = (char*)d_ws;
    __hip_bfloat16* cbf  = (__hip_bfloat16*)(w);
    __hip_bfloat16* z1   = (__hip_bfloat16*)(w + (size_t)(1 << 20));
    __hip_bfloat16* z2   = (__hip_bfloat16*)(w + (size_t)(2 << 20));
    __hip_bfloat16* xb   = (__hip_bfloat16*)(w + (size_t)(3 << 20));
    __hip_bfloat16* hbuf = (__hip_bfloat16*)(w + (size_t)(4 << 20));
    __hip_bfloat16* W1b  = (__hip_bfloat16*)(w + (size_t)(5 << 20));
    __hip_bfloat16* W3b  = (__hip_bfloat16*)(w + (size_t)(6 << 20));
    __hip_bfloat16* Wihb = (__hip_bfloat16*)(w + (size_t)(7 << 20));
    __hip_bfloat16* Whhb = (__hip_bfloat16*)(w + (size_t)(9 << 20));

    hipMemsetAsync(cbf,  0, (size_t)(1 << 20), stream);  // c0 = 0 (bf16 shadow)
    hipMemsetAsync(hbuf, 0, (size_t)(1 << 20), stream);  // h0 = 0

    pack_kernel<<<1536, 256, 0, stream>>>(W1, W3, Wih, Whh, W1b, W3b, Wihb, Whhb);

    void* args[] = {
        (void*)&sv, (void*)&W2, (void*)&b2, (void*)&W1b, (void*)&b1,
        (void*)&W3b, (void*)&b3, (void*)&Wihb, (void*)&Whhb,
        (void*)&bih, (void*)&bhh, (void*)&cbf, (void*)&hbuf,
        (void*)&z1, (void*)&z2, (void*)&xb, (void*)&out };
    hipLaunchCooperativeKernel(rnn_kernel, dim3(256), dim3(512), args, 0, stream);
}

// Round 3
// 7672.160 us; speedup vs baseline: 3.7743x; 2.0728x over previous
//
#include <hip/hip_runtime.h>
#include <hip/hip_bf16.h>

#define T_SZ 128
#define DPV  10

// Persistent cooperative LSTM, 256 blocks x 512 threads (1/CU, 8 waves).
// Block (g8 = blk&7, nu = blk>>3) owns batch rows [g8*128,+128) and output
// cols [nu*16,+16). The 8 row-teams are data-independent, so barriers are
// per-team (32 blocks): hand-rolled monotonic counter barrier, leader-only
// agent-scope atomics/fences, tight s_sleep(1) spin — replaces cg::grid.sync
// (~40 us each, was ~120 us/step = the round-2 bottleneck).
// Split-phase: independent work (h@Whh, z2(t+1)) runs between arrive & wait.

typedef __attribute__((ext_vector_type(8))) short bfrag8;
typedef __attribute__((ext_vector_type(4))) float floatx4;

#define MFMA __builtin_amdgcn_mfma_f32_16x16x32_bf16

static __device__ __forceinline__ bfrag8 load8(const __hip_bfloat16* p) {
    return *(const bfrag8*)(const void*)p;  // 16B-aligned by construction
}
static __device__ __forceinline__ float sigm(float x) {
    return 1.0f / (1.0f + __expf(-x));
}
// LDS byte address for (row, kbyte) of a [64 rows x 1024B] weight slice,
// XOR-swizzled so 16 lanes reading 16 rows at the same k are <=2-way.
static __device__ __forceinline__ int swz(int row, int kb) {
    return row * 1024 + (kb ^ ((row & 7) << 4));
}

// ---------------------------------------------------------------------------
// One-time weight conversion: fp32 -> bf16 for W1, W3, Wih, Whh.
// ---------------------------------------------------------------------------
__global__ __launch_bounds__(256) void pack_kernel(
    const float* __restrict__ W1, const float* __restrict__ W3,
    const float* __restrict__ Wih, const float* __restrict__ Whh,
    __hip_bfloat16* __restrict__ W1b, __hip_bfloat16* __restrict__ W3b,
    __hip_bfloat16* __restrict__ Wihb, __hip_bfloat16* __restrict__ Whhb)
{
    const size_t e = ((size_t)blockIdx.x * 256 + threadIdx.x) * 8;
    const float* src; __hip_bfloat16* dst; size_t off;
    if (e < 524288)        { src = W1;  dst = W1b;  off = e; }
    else if (e < 1048576)  { src = W3;  dst = W3b;  off = e - 524288; }
    else if (e < 2097152)  { src = Wih; dst = Wihb; off = e - 1048576; }
    else                   { src = Whh; dst = Whhb; off = e - 2097152; }
#pragma unroll
    for (int j = 0; j < 8; ++j) dst[off + j] = __float2bfloat16(src[off + j]);
}

// ---------------------------------------------------------------------------
// MFMA 16x16x32_bf16 layouts (HW-verified):
//   A-frag: lane l holds A[m=l&15][k=(l>>4)*8+j]
//   B-frag: lane l holds W[n=l&15][k=(l>>4)*8+j]  (K-contig row-major)
//   C/D:    lane l reg r -> row=(l>>4)*4+r, col=l&15
// ---------------------------------------------------------------------------
__global__ __launch_bounds__(512) void rnn_kernel(
    const float* __restrict__ sv,
    const float* __restrict__ W2, const float* __restrict__ b2,
    const __hip_bfloat16* __restrict__ W1b, const float* __restrict__ b1,
    const __hip_bfloat16* __restrict__ W3b, const float* __restrict__ b3,
    const __hip_bfloat16* __restrict__ Wihb, const __hip_bfloat16* __restrict__ Whhb,
    const float* __restrict__ bih, const float* __restrict__ bhh,
    __hip_bfloat16* __restrict__ cbf, __hip_bfloat16* __restrict__ hbuf,
    __hip_bfloat16* __restrict__ z1, __hip_bfloat16* __restrict__ z2,
    __hip_bfloat16* __restrict__ xbuf,
    unsigned int* bar,
    float* __restrict__ out)
{
    __shared__ __align__(16) char lds[131072];   // [0,64K): Wih; [64K,128K): Whh

    const int blk  = blockIdx.x;
    const int g8   = blk & 7;        // row-team id (XCD-affine under round-robin)
    const int nu   = blk >> 3;       // 0..31 n-slice
    const int m0   = g8 << 7;        // 128 batch rows
    const int j0   = nu << 4;        // 16 output cols
    const int tid  = threadIdx.x;
    const int w    = tid >> 6;
    const int lane = tid & 63;
    const int l15  = lane & 15;
    const int quad = lane >> 4;

    unsigned int* cnt = bar + (size_t)g8 * 64;   // 256B-separated team counters
    unsigned int btarget = 0;

    // team barrier, split-phase: ARRIVE ... independent work ... WAITB
#define ARRIVE() do { __syncthreads();                                          \
        if (tid == 0) {                                                         \
            __builtin_amdgcn_fence(__ATOMIC_RELEASE, "agent");                  \
            __hip_atomic_fetch_add(cnt, 1u, __ATOMIC_RELAXED,                   \
                                   __HIP_MEMORY_SCOPE_AGENT);                   \
        }                                                                       \
        btarget += 32; } while (0)
#define WAITB() do { if (tid == 0) {                                            \
            while (__hip_atomic_load(cnt, __ATOMIC_RELAXED,                     \
                                     __HIP_MEMORY_SCOPE_AGENT) < btarget)       \
                __builtin_amdgcn_s_sleep(1);                                    \
            __builtin_amdgcn_fence(__ATOMIC_ACQUIRE, "agent");                  \
        }                                                                       \
        __syncthreads(); } while (0)

    // ---- stage Wih/Whh j-slices into LDS once (64 rows x 512 K each) ----
    for (int i = tid; i < 4096; i += 512) {
        const int row  = i >> 6;             // 0..63 = gate*16 + jj
        const int kb   = (i & 63) << 4;      // byte offset, 16B chunks
        const int gate = row >> 4, jj = row & 15;
        const size_t goff = ((size_t)(gate * 512 + j0 + jj)) * 512 + (kb >> 1);
        *(bfrag8*)(lds +         swz(row, kb)) = load8(Wihb + goff);
        *(bfrag8*)(lds + 65536 + swz(row, kb)) = load8(Whhb + goff);
    }
    __syncthreads();

    const int arow = m0 + w * 16 + l15;       // A-fragment row for this lane
    const int orow = m0 + w * 16 + quad * 4;  // output row base (+r)
    const int col  = j0 + l15;                // output col
    const int kq   = quad << 4;               // lane's 16B offset in a K-row

    // per-lane constants for all 128 steps
    const float b1v = b1[col];
    const float b3v = b3[col];
    const float b2v = b2[col];
    const float biv = bih[col]        + bhh[col];
    const float bfv = bih[512 + col]  + bhh[512 + col];
    const float bgv = bih[1024 + col] + bhh[1024 + col];
    const float bov = bih[1536 + col] + bhh[1536 + col];
    float w2r[DPV];
#pragma unroll
    for (int k = 0; k < DPV; ++k) w2r[k] = W2[(size_t)col * DPV + k];

    const __hip_bfloat16* hA  = hbuf + (size_t)arow * 512 + quad * 8;
    const __hip_bfloat16* cA  = cbf  + (size_t)arow * 512 + quad * 8;
    const __hip_bfloat16* z1A = z1   + (size_t)arow * 512 + quad * 8;
    const __hip_bfloat16* z2A = z2   + (size_t)arow * 512 + quad * 8;
    const __hip_bfloat16* xA  = xbuf + (size_t)arow * 512 + quad * 8;
    const __hip_bfloat16* w1  = W1b + (size_t)col * 1024 + quad * 8;
    const __hip_bfloat16* w3  = W3b + (size_t)col * 1024 + quad * 8;
    const int xorl = (l15 & 7) << 4;          // lane's LDS swizzle term

    // prologue: z2(t=0) = relu(sv_0 @ W2^T + b2)
#pragma unroll
    for (int r = 0; r < 4; ++r) {
        const float* svp = sv + ((size_t)(orow + r) * T_SZ + 0) * DPV;
        float acc = b2v;
#pragma unroll
        for (int k = 0; k < DPV; ++k) acc += svp[k] * w2r[k];
        z2[(size_t)(orow + r) * 512 + col] = __float2bfloat16(fmaxf(acc, 0.f));
    }

    floatx4 creg = {0.f, 0.f, 0.f, 0.f};      // fp32 c-state, register-resident

    for (int t = 0; t < T_SZ; ++t) {
        // -------- P1: z1 = relu(h@W1a^T + c@W1b^T + b1); store; arrive --------
        floatx4 az = {0.f, 0.f, 0.f, 0.f};
#pragma unroll
        for (int k0 = 0; k0 < 512; k0 += 32) {
            az = MFMA(load8(hA + k0), load8(w1 + k0),       az, 0, 0, 0);
            az = MFMA(load8(cA + k0), load8(w1 + 512 + k0), az, 0, 0, 0);
        }
#pragma unroll
        for (int r = 0; r < 4; ++r)
            z1[(size_t)(orow + r) * 512 + col] =
                __float2bfloat16(fmaxf(az[r] + b1v, 0.f));
        ARRIVE();
        // -------- window 1 (hides barrier 1): gacc = h @ Whh^T (LDS) --------
        // h is stable here: no teammate can reach P3 (h-writes) before our
        // arrive at barrier 2, which follows this window.
        floatx4 gacc[4];
#pragma unroll
        for (int G = 0; G < 4; ++G) gacc[G] = (floatx4){0.f, 0.f, 0.f, 0.f};
#pragma unroll
        for (int k0 = 0; k0 < 512; k0 += 32) {
            bfrag8 a = load8(hA + k0);
#pragma unroll
            for (int G = 0; G < 4; ++G) {
                bfrag8 b = *(const bfrag8*)(lds + 65536 +
                    (G * 16 + l15) * 1024 + ((k0 * 2 + kq) ^ xorl));
                gacc[G] = MFMA(a, b, gacc[G], 0, 0, 0);
            }
        }
        WAITB();
        // -------- P2: x = relu(z1@W3a^T + z2@W3b^T + b3); store; arrive --------
        floatx4 ax = {0.f, 0.f, 0.f, 0.f};
#pragma unroll
        for (int k0 = 0; k0 < 512; k0 += 32) {
            ax = MFMA(load8(z1A + k0), load8(w3 + k0),       ax, 0, 0, 0);
            ax = MFMA(load8(z2A + k0), load8(w3 + 512 + k0), ax, 0, 0, 0);
        }
#pragma unroll
        for (int r = 0; r < 4; ++r)
            xbuf[(size_t)(orow + r) * 512 + col] =
                __float2bfloat16(fmaxf(ax[r] + b3v, 0.f));
        ARRIVE();
        WAITB();   // (window 2 empty: everything else depends on x or writes h)
        // -------- P3: gacc += x@Wih^T (LDS); LSTM cell; store h,c,out --------
#pragma unroll
        for (int k0 = 0; k0 < 512; k0 += 32) {
            bfrag8 a = load8(xA + k0);
#pragma unroll
            for (int G = 0; G < 4; ++G) {
                bfrag8 b = *(const bfrag8*)(lds +
                    (G * 16 + l15) * 1024 + ((k0 * 2 + kq) ^ xorl));
                gacc[G] = MFMA(a, b, gacc[G], 0, 0, 0);
            }
        }
#pragma unroll
        for (int r = 0; r < 4; ++r) {
            const float iv = sigm(gacc[0][r] + biv);
            const float fv = sigm(gacc[1][r] + bfv);
            const float gv = tanhf(gacc[2][r] + bgv);
            const float ov = sigm(gacc[3][r] + bov);
            const float cn = fv * creg[r] + iv * gv;
            const float hv = ov * tanhf(cn);
            creg[r] = cn;
            cbf [(size_t)(orow + r) * 512 + col] = __float2bfloat16(cn);
            hbuf[(size_t)(orow + r) * 512 + col] = __float2bfloat16(hv);
            out[((size_t)(orow + r) * T_SZ + t) * 512 + col] = hv;  // fp32
        }
        ARRIVE();
        // -------- window 3 (hides barrier 3): z2(t+1), safe to store --------
        // all teammates passed barrier 2, so no one still reads z2(t).
        if (t + 1 < T_SZ) {
#pragma unroll
            for (int r = 0; r < 4; ++r) {
                const float* svp = sv + ((size_t)(orow + r) * T_SZ + t + 1) * DPV;
                float acc = b2v;
#pragma unroll
                for (int k = 0; k < DPV; ++k) acc += svp[k] * w2r[k];
                z2[(size_t)(orow + r) * 512 + col] =
                    __float2bfloat16(fmaxf(acc, 0.f));
            }
        }
        WAITB();
    }
#undef ARRIVE
#undef WAITB
}

// ---------------------------------------------------------------------------
// Workspace layout (12 MB):
//   0 MB  cbf   bf16 [1024x512]   (1 MB)
//   1 MB  z1    bf16 [1024x512]   (1 MB)
//   2 MB  z2    bf16 [1024x512]   (1 MB)
//   3 MB  x     bf16 [1024x512]   (1 MB)
//   4 MB  h     bf16 [1024x512]   (1 MB)
//   5 MB  W1b   bf16 [512x1024]   (1 MB)
//   6 MB  W3b   bf16 [512x1024]   (1 MB)
//   7 MB  Wihb  bf16 [2048x512]   (2 MB)
//   9 MB  Whhb  bf16 [2048x512]   (2 MB)
//  11 MB  bar   u32 team barrier counters (2 KB, memset each launch)
// ---------------------------------------------------------------------------
extern "C" void kernel_launch(void* const* d_in, const int* in_sizes, int n_in,
                              void* d_out, int out_size, void* d_ws, size_t ws_size,
                              hipStream_t stream) {
    (void)in_sizes; (void)n_in; (void)out_size; (void)ws_size;

    const float* sv  = (const float*)d_in[0];
    const float* W1  = (const float*)d_in[1];
    const float* b1  = (const float*)d_in[2];
    const float* W2  = (const float*)d_in[3];
    const float* b2  = (const float*)d_in[4];
    const float* W3  = (const float*)d_in[5];
    const float* b3  = (const float*)d_in[6];
    const float* Wih = (const float*)d_in[7];
    const float* Whh = (const float*)d_in[8];
    const float* bih = (const float*)d_in[9];
    const float* bhh = (const float*)d_in[10];
    float* out = (float*)d_out;

    char* w = (char*)d_ws;
    __hip_bfloat16* cbf  = (__hip_bfloat16*)(w);
    __hip_bfloat16* z1   = (__hip_bfloat16*)(w + (size_t)(1 << 20));
    __hip_bfloat16* z2   = (__hip_bfloat16*)(w + (size_t)(2 << 20));
    __hip_bfloat16* xb   = (__hip_bfloat16*)(w + (size_t)(3 << 20));
    __hip_bfloat16* hbuf = (__hip_bfloat16*)(w + (size_t)(4 << 20));
    __hip_bfloat16* W1b  = (__hip_bfloat16*)(w + (size_t)(5 << 20));
    __hip_bfloat16* W3b  = (__hip_bfloat16*)(w + (size_t)(6 << 20));
    __hip_bfloat16* Wihb = (__hip_bfloat16*)(w + (size_t)(7 << 20));
    __hip_bfloat16* Whhb = (__hip_bfloat16*)(w + (size_t)(9 << 20));
    unsigned int*   bar  = (unsigned int*)  (w + (size_t)(11 << 20));

    hipMemsetAsync(cbf,  0, (size_t)(1 << 20), stream);  // c0 = 0 (bf16 shadow)
    hipMemsetAsync(hbuf, 0, (size_t)(1 << 20), stream);  // h0 = 0
    hipMemsetAsync(bar,  0, 2048, stream);               // barrier epoch reset

    pack_kernel<<<1536, 256, 0, stream>>>(W1, W3, Wih, Whh, W1b, W3b, Wihb, Whhb);

    void* args[] = {
        (void*)&sv, (void*)&W2, (void*)&b2, (void*)&W1b, (void*)&b1,
        (void*)&W3b, (void*)&b3, (void*)&Wihb, (void*)&Whhb,
        (void*)&bih, (void*)&bhh, (void*)&cbf, (void*)&hbuf,
        (void*)&z1, (void*)&z2, (void*)&xb, (void*)&bar, (void*)&out };
    hipLaunchCooperativeKernel(rnn_kernel, dim3(256), dim3(512), args, 0, stream);
}

// Round 4
// 5171.854 us; speedup vs baseline: 5.5989x; 1.4834x over previous
//
#include <hip/hip_runtime.h>
#include <hip/hip_bf16.h>

#define T_SZ 128
#define DPV  10

// Persistent cooperative LSTM, 256 blocks x 512 threads (1 block/CU, 8 waves).
// Teams of 32 blocks own 128 batch rows x all 512 cols; block owns 16 cols
// (Wih/Whh col-slices pinned in 128 KB LDS). Round-3 bottleneck: agent-scope
// acquire fences wiped per-XCD L2 3x/step -> 37.5 MB/step refetch = the whole
// 59 us/step. This version detects the real block->XCD mapping at runtime
// (s_getreg HW_REG_XCC_ID) and, when every XCD hosts exactly 32 blocks,
// forms teams FROM XCD residency so producer/consumer share a coherent L2:
// barrier then needs only vmcnt-drain + relaxed agent atomic + L1-only
// buffer_inv (CDNA L1 is write-through; data is already in shared L2).
// Weights stay L2-resident forever. If the mapping check fails -> round-3
// agent-fence path (correct under any mapping, ~7.7 ms).

typedef __attribute__((ext_vector_type(8))) short bfrag8;
typedef __attribute__((ext_vector_type(4))) float floatx4;

#define MFMA __builtin_amdgcn_mfma_f32_16x16x32_bf16

static __device__ __forceinline__ bfrag8 load8(const __hip_bfloat16* p) {
    return *(const bfrag8*)(const void*)p;  // 16B-aligned by construction
}
static __device__ __forceinline__ float sigm(float x) {
    return 1.0f / (1.0f + __expf(-x));
}
// LDS byte address for (row, kbyte) of a [64 rows x 1024B] weight slice,
// XOR-swizzled so 16 lanes reading 16 rows at the same k are <=2-way.
static __device__ __forceinline__ int swz(int row, int kb) {
    return row * 1024 + (kb ^ ((row & 7) << 4));
}

// ---------------------------------------------------------------------------
// One-time weight conversion: fp32 -> bf16 for W1, W3, Wih, Whh.
// ---------------------------------------------------------------------------
__global__ __launch_bounds__(256) void pack_kernel(
    const float* __restrict__ W1, const float* __restrict__ W3,
    const float* __restrict__ Wih, const float* __restrict__ Whh,
    __hip_bfloat16* __restrict__ W1b, __hip_bfloat16* __restrict__ W3b,
    __hip_bfloat16* __restrict__ Wihb, __hip_bfloat16* __restrict__ Whhb)
{
    const size_t e = ((size_t)blockIdx.x * 256 + threadIdx.x) * 8;
    const float* src; __hip_bfloat16* dst; size_t off;
    if (e < 524288)        { src = W1;  dst = W1b;  off = e; }
    else if (e < 1048576)  { src = W3;  dst = W3b;  off = e - 524288; }
    else if (e < 2097152)  { src = Wih; dst = Wihb; off = e - 1048576; }
    else                   { src = Whh; dst = Whhb; off = e - 2097152; }
#pragma unroll
    for (int j = 0; j < 8; ++j) dst[off + j] = __float2bfloat16(src[off + j]);
}

// ---------------------------------------------------------------------------
// Team barrier, split-phase. FAST: XCD-local teams -> no L2 invalidation,
// L1-only buffer_inv on the wait side. SAFE: agent fences (any mapping).
// ---------------------------------------------------------------------------
template<bool FAST>
static __device__ __forceinline__ void arrive_(unsigned* cnt, int tid) {
    __syncthreads();                 // drains vmcnt(0): stores are in L2
    if (tid == 0) {
        if (!FAST) __builtin_amdgcn_fence(__ATOMIC_RELEASE, "agent");
        __hip_atomic_fetch_add(cnt, 1u, __ATOMIC_RELAXED,
                               __HIP_MEMORY_SCOPE_AGENT);
    }
}
template<bool FAST>
static __device__ __forceinline__ void waitb_(unsigned* cnt, int tid,
                                              unsigned target) {
    __syncthreads();                 // all waves' window loads retired first
    if (tid == 0) {
        while (__hip_atomic_load(cnt, __ATOMIC_RELAXED,
                                 __HIP_MEMORY_SCOPE_AGENT) < target)
            __builtin_amdgcn_s_sleep(1);
        if (FAST) asm volatile("buffer_inv" ::: "memory");   // L1 only
        else __builtin_amdgcn_fence(__ATOMIC_ACQUIRE, "agent");
    }
    __syncthreads();
}

// ---------------------------------------------------------------------------
// MFMA 16x16x32_bf16 layouts (HW-verified):
//   A-frag: lane l holds A[m=l&15][k=(l>>4)*8+j]
//   B-frag: lane l holds W[n=l&15][k=(l>>4)*8+j]  (K-contig row-major)
//   C/D:    lane l reg r -> row=(l>>4)*4+r, col=l&15
// ---------------------------------------------------------------------------
template<bool FAST>
static __device__ void main_loop(
    const float* __restrict__ sv,
    const float* __restrict__ W2, const float* __restrict__ b2,
    const __hip_bfloat16* __restrict__ W1b, const float* __restrict__ b1,
    const __hip_bfloat16* __restrict__ W3b, const float* __restrict__ b3,
    const __hip_bfloat16* __restrict__ Wihb, const __hip_bfloat16* __restrict__ Whhb,
    const float* __restrict__ bih, const float* __restrict__ bhh,
    __hip_bfloat16* __restrict__ cbf, __hip_bfloat16* __restrict__ hbuf,
    __hip_bfloat16* __restrict__ z1, __hip_bfloat16* __restrict__ z2,
    __hip_bfloat16* __restrict__ xbuf, float* __restrict__ out,
    char* lds, unsigned* cnt, int g8, int nu, int tid)
{
    const int m0   = g8 << 7;        // 128 batch rows
    const int j0   = nu << 4;        // 16 output cols
    const int w    = tid >> 6;
    const int lane = tid & 63;
    const int l15  = lane & 15;
    const int quad = lane >> 4;
    unsigned btarget = 0;

    // ---- stage Wih/Whh j-slices into LDS (64 rows x 512 K each) ----
    for (int i = tid; i < 4096; i += 512) {
        const int row  = i >> 6;             // 0..63 = gate*16 + jj
        const int kb   = (i & 63) << 4;      // byte offset, 16B chunks
        const int gate = row >> 4, jj = row & 15;
        const size_t goff = ((size_t)(gate * 512 + j0 + jj)) * 512 + (kb >> 1);
        *(bfrag8*)(lds +         swz(row, kb)) = load8(Wihb + goff);
        *(bfrag8*)(lds + 65536 + swz(row, kb)) = load8(Whhb + goff);
    }
    __syncthreads();

    const int arow = m0 + w * 16 + l15;       // A-fragment row for this lane
    const int orow = m0 + w * 16 + quad * 4;  // output row base (+r)
    const int col  = j0 + l15;                // output col
    const int kq   = quad << 4;               // lane's 16B offset in a K-row

    // per-lane constants for all 128 steps
    const float b1v = b1[col];
    const float b3v = b3[col];
    const float b2v = b2[col];
    const float biv = bih[col]        + bhh[col];
    const float bfv = bih[512 + col]  + bhh[512 + col];
    const float bgv = bih[1024 + col] + bhh[1024 + col];
    const float bov = bih[1536 + col] + bhh[1536 + col];
    float w2r[DPV];
#pragma unroll
    for (int k = 0; k < DPV; ++k) w2r[k] = W2[(size_t)col * DPV + k];

    const __hip_bfloat16* hA  = hbuf + (size_t)arow * 512 + quad * 8;
    const __hip_bfloat16* cA  = cbf  + (size_t)arow * 512 + quad * 8;
    const __hip_bfloat16* z1A = z1   + (size_t)arow * 512 + quad * 8;
    const __hip_bfloat16* z2A = z2   + (size_t)arow * 512 + quad * 8;
    const __hip_bfloat16* xA  = xbuf + (size_t)arow * 512 + quad * 8;
    const __hip_bfloat16* w1  = W1b + (size_t)col * 1024 + quad * 8;
    const __hip_bfloat16* w3  = W3b + (size_t)col * 1024 + quad * 8;
    const int xorl = (l15 & 7) << 4;          // lane's LDS swizzle term

    // prologue: z2(t=0) = relu(sv_0 @ W2^T + b2)
#pragma unroll
    for (int r = 0; r < 4; ++r) {
        const float* svp = sv + ((size_t)(orow + r) * T_SZ + 0) * DPV;
        float acc = b2v;
#pragma unroll
        for (int k = 0; k < DPV; ++k) acc += svp[k] * w2r[k];
        z2[(size_t)(orow + r) * 512 + col] = __float2bfloat16(fmaxf(acc, 0.f));
    }

    floatx4 creg = {0.f, 0.f, 0.f, 0.f};      // fp32 c-state, register-resident

    for (int t = 0; t < T_SZ; ++t) {
        // -------- P1: z1 = relu(h@W1a^T + c@W1b^T + b1); h-frags kept --------
        bfrag8 hf[16];                        // h(t-1), reused in window 1
        floatx4 az = {0.f, 0.f, 0.f, 0.f};
#pragma unroll
        for (int i = 0; i < 16; ++i) {
            const int k0 = i * 32;
            hf[i] = load8(hA + k0);
            az = MFMA(hf[i], load8(w1 + k0), az, 0, 0, 0);
        }
#pragma unroll
        for (int k0 = 0; k0 < 512; k0 += 32)
            az = MFMA(load8(cA + k0), load8(w1 + 512 + k0), az, 0, 0, 0);
#pragma unroll
        for (int r = 0; r < 4; ++r)
            z1[(size_t)(orow + r) * 512 + col] =
                __float2bfloat16(fmaxf(az[r] + b1v, 0.f));
        arrive_<FAST>(cnt, tid);  btarget += 32;
        // -------- window 1 (hides barrier 1): gacc = h @ Whh^T (LDS) --------
        // h stable: teammates can't reach P3's h-writes before our arrive at
        // barrier 2, which follows this window.
        floatx4 gacc[4];
#pragma unroll
        for (int G = 0; G < 4; ++G) gacc[G] = (floatx4){0.f, 0.f, 0.f, 0.f};
#pragma unroll
        for (int i = 0; i < 16; ++i) {
            const int k0 = i * 32;
#pragma unroll
            for (int G = 0; G < 4; ++G) {
                bfrag8 b = *(const bfrag8*)(lds + 65536 +
                    (G * 16 + l15) * 1024 + ((k0 * 2 + kq) ^ xorl));
                gacc[G] = MFMA(hf[i], b, gacc[G], 0, 0, 0);
            }
        }
        waitb_<FAST>(cnt, tid, btarget);
        // -------- P2: x = relu(z1@W3a^T + z2@W3b^T + b3) --------
        floatx4 ax = {0.f, 0.f, 0.f, 0.f};
#pragma unroll
        for (int k0 = 0; k0 < 512; k0 += 32) {
            ax = MFMA(load8(z1A + k0), load8(w3 + k0),       ax, 0, 0, 0);
            ax = MFMA(load8(z2A + k0), load8(w3 + 512 + k0), ax, 0, 0, 0);
        }
#pragma unroll
        for (int r = 0; r < 4; ++r)
            xbuf[(size_t)(orow + r) * 512 + col] =
                __float2bfloat16(fmaxf(ax[r] + b3v, 0.f));
        arrive_<FAST>(cnt, tid);  btarget += 32;
        waitb_<FAST>(cnt, tid, btarget);   // window 2 empty (all depends on x)
        // -------- P3: gacc += x@Wih^T (LDS); LSTM cell; store h,c,out --------
#pragma unroll
        for (int k0 = 0; k0 < 512; k0 += 32) {
            bfrag8 a = load8(xA + k0);
#pragma unroll
            for (int G = 0; G < 4; ++G) {
                bfrag8 b = *(const bfrag8*)(lds +
                    (G * 16 + l15) * 1024 + ((k0 * 2 + kq) ^ xorl));
                gacc[G] = MFMA(a, b, gacc[G], 0, 0, 0);
            }
        }
#pragma unroll
        for (int r = 0; r < 4; ++r) {
            const float iv = sigm(gacc[0][r] + biv);
            const float fv = sigm(gacc[1][r] + bfv);
            const float gv = tanhf(gacc[2][r] + bgv);
            const float ov = sigm(gacc[3][r] + bov);
            const float cn = fv * creg[r] + iv * gv;
            const float hv = ov * tanhf(cn);
            creg[r] = cn;
            cbf [(size_t)(orow + r) * 512 + col] = __float2bfloat16(cn);
            hbuf[(size_t)(orow + r) * 512 + col] = __float2bfloat16(hv);
            out[((size_t)(orow + r) * T_SZ + t) * 512 + col] = hv;  // fp32
        }
        arrive_<FAST>(cnt, tid);  btarget += 32;
        // -------- window 3 (hides barrier 3): z2(t+1) --------
        // all teammates passed barrier 2, so no one still reads z2(t).
        if (t + 1 < T_SZ) {
#pragma unroll
            for (int r = 0; r < 4; ++r) {
                const float* svp = sv + ((size_t)(orow + r) * T_SZ + t + 1) * DPV;
                float acc = b2v;
#pragma unroll
                for (int k = 0; k < DPV; ++k) acc += svp[k] * w2r[k];
                z2[(size_t)(orow + r) * 512 + col] =
                    __float2bfloat16(fmaxf(acc, 0.f));
            }
        }
        waitb_<FAST>(cnt, tid, btarget);
    }
}

// ---------------------------------------------------------------------------
// Kernel: XCD detection -> adaptive teams -> FAST or SAFE main loop.
// bar layout (u32 idx): [g8*64] team counters; [512] grid counter;
// [640..895] xcdtab.
// ---------------------------------------------------------------------------
__global__ __launch_bounds__(512) void rnn_kernel(
    const float* __restrict__ sv,
    const float* __restrict__ W2, const float* __restrict__ b2,
    const __hip_bfloat16* __restrict__ W1b, const float* __restrict__ b1,
    const __hip_bfloat16* __restrict__ W3b, const float* __restrict__ b3,
    const __hip_bfloat16* __restrict__ Wihb, const __hip_bfloat16* __restrict__ Whhb,
    const float* __restrict__ bih, const float* __restrict__ bhh,
    __hip_bfloat16* __restrict__ cbf, __hip_bfloat16* __restrict__ hbuf,
    __hip_bfloat16* __restrict__ z1, __hip_bfloat16* __restrict__ z2,
    __hip_bfloat16* __restrict__ xbuf,
    unsigned int* bar,
    float* __restrict__ out)
{
    __shared__ __align__(16) char lds[131072];
    const int blk = blockIdx.x;
    const int tid = threadIdx.x;

    // ---- detect physical XCD of this block ----
    unsigned xcd;
    asm volatile("s_getreg_b32 %0, hwreg(HW_REG_XCC_ID)" : "=s"(xcd));
    unsigned* xcdtab = bar + 640;
    unsigned* gbar   = bar + 512;
    if (tid == 0)
        __hip_atomic_store(xcdtab + blk, xcd, __ATOMIC_RELAXED,
                           __HIP_MEMORY_SCOPE_AGENT);
    // one full-grid barrier (agent fences: correct under any mapping)
    __syncthreads();
    if (tid == 0) {
        __builtin_amdgcn_fence(__ATOMIC_RELEASE, "agent");
        __hip_atomic_fetch_add(gbar, 1u, __ATOMIC_RELAXED,
                               __HIP_MEMORY_SCOPE_AGENT);
        while (__hip_atomic_load(gbar, __ATOMIC_RELAXED,
                                 __HIP_MEMORY_SCOPE_AGENT) < 256u)
            __builtin_amdgcn_s_sleep(1);
        __builtin_amdgcn_fence(__ATOMIC_ACQUIRE, "agent");
    }
    __syncthreads();

    // ---- pull table into LDS; histogram; decide FAST eligibility ----
    unsigned* tab = (unsigned*)lds;          // reused, overwritten by staging
    if (tid < 256)
        tab[tid] = __hip_atomic_load(xcdtab + tid, __ATOMIC_RELAXED,
                                     __HIP_MEMORY_SCOPE_AGENT);
    else if (tid < 272)
        tab[tid] = 0;                        // hist[8] @256, flag @264
    __syncthreads();
    if (tid < 256) {
        unsigned x = tab[tid];
        if (x > 7) atomicOr(&tab[264], 1u);
        else       atomicAdd(&tab[256 + x], 1u);
    }
    __syncthreads();
    bool fast = (tab[264] == 0);
#pragma unroll
    for (int i = 0; i < 8; ++i) fast = fast && (tab[256 + i] == 32u);
    const unsigned myx = tab[blk];
    int rank = 0;
    for (int j = 0; j < blk; ++j) rank += (tab[j] == myx);  // rank within XCD
    const int g8 = fast ? (int)myx : (blk & 7);
    const int nu = fast ? rank     : (blk >> 3);
    __syncthreads();                          // done with tab; lds reused

    unsigned* cnt = bar + (size_t)g8 * 64;    // 256B-separated team counters
    if (fast)
        main_loop<true >(sv, W2, b2, W1b, b1, W3b, b3, Wihb, Whhb, bih, bhh,
                         cbf, hbuf, z1, z2, xbuf, out, lds, cnt, g8, nu, tid);
    else
        main_loop<false>(sv, W2, b2, W1b, b1, W3b, b3, Wihb, Whhb, bih, bhh,
                         cbf, hbuf, z1, z2, xbuf, out, lds, cnt, g8, nu, tid);
}

// ---------------------------------------------------------------------------
// Workspace layout (12 MB):
//   0 MB  cbf   bf16 [1024x512]   (1 MB)
//   1 MB  z1    bf16 [1024x512]   (1 MB)
//   2 MB  z2    bf16 [1024x512]   (1 MB)
//   3 MB  x     bf16 [1024x512]   (1 MB)
//   4 MB  h     bf16 [1024x512]   (1 MB)
//   5 MB  W1b   bf16 [512x1024]   (1 MB)
//   6 MB  W3b   bf16 [512x1024]   (1 MB)
//   7 MB  Wihb  bf16 [2048x512]   (2 MB)
//   9 MB  Whhb  bf16 [2048x512]   (2 MB)
//  11 MB  bar   u32: team counters / grid counter / xcdtab (4 KB, memset)
// ---------------------------------------------------------------------------
extern "C" void kernel_launch(void* const* d_in, const int* in_sizes, int n_in,
                              void* d_out, int out_size, void* d_ws, size_t ws_size,
                              hipStream_t stream) {
    (void)in_sizes; (void)n_in; (void)out_size; (void)ws_size;

    const float* sv  = (const float*)d_in[0];
    const float* W1  = (const float*)d_in[1];
    const float* b1  = (const float*)d_in[2];
    const float* W2  = (const float*)d_in[3];
    const float* b2  = (const float*)d_in[4];
    const float* W3  = (const float*)d_in[5];
    const float* b3  = (const float*)d_in[6];
    const float* Wih = (const float*)d_in[7];
    const float* Whh = (const float*)d_in[8];
    const float* bih = (const float*)d_in[9];
    const float* bhh = (const float*)d_in[10];
    float* out = (float*)d_out;

    char* w = (char*)d_ws;
    __hip_bfloat16* cbf  = (__hip_bfloat16*)(w);
    __hip_bfloat16* z1   = (__hip_bfloat16*)(w + (size_t)(1 << 20));
    __hip_bfloat16* z2   = (__hip_bfloat16*)(w + (size_t)(2 << 20));
    __hip_bfloat16* xb   = (__hip_bfloat16*)(w + (size_t)(3 << 20));
    __hip_bfloat16* hbuf = (__hip_bfloat16*)(w + (size_t)(4 << 20));
    __hip_bfloat16* W1b  = (__hip_bfloat16*)(w + (size_t)(5 << 20));
    __hip_bfloat16* W3b  = (__hip_bfloat16*)(w + (size_t)(6 << 20));
    __hip_bfloat16* Wihb = (__hip_bfloat16*)(w + (size_t)(7 << 20));
    __hip_bfloat16* Whhb = (__hip_bfloat16*)(w + (size_t)(9 << 20));
    unsigned int*   bar  = (unsigned int*)  (w + (size_t)(11 << 20));

    hipMemsetAsync(cbf,  0, (size_t)(1 << 20), stream);  // c0 = 0 (bf16 shadow)
    hipMemsetAsync(hbuf, 0, (size_t)(1 << 20), stream);  // h0 = 0
    hipMemsetAsync(bar,  0, 4096, stream);               // barriers + xcdtab

    pack_kernel<<<1536, 256, 0, stream>>>(W1, W3, Wih, Whh, W1b, W3b, Wihb, Whhb);

    void* args[] = {
        (void*)&sv, (void*)&W2, (void*)&b2, (void*)&W1b, (void*)&b1,
        (void*)&W3b, (void*)&b3, (void*)&Wihb, (void*)&Whhb,
        (void*)&bih, (void*)&bhh, (void*)&cbf, (void*)&hbuf,
        (void*)&z1, (void*)&z2, (void*)&xb, (void*)&bar, (void*)&out };
    hipLaunchCooperativeKernel(rnn_kernel, dim3(256), dim3(512), args, 0, stream);
}